// Round 5
// baseline (749.447 us; speedup 1.0000x reference)
//
#include <hip/hip_runtime.h>

typedef __attribute__((ext_vector_type(8))) short short8;
typedef __attribute__((ext_vector_type(8))) unsigned short ushort8;
typedef __attribute__((ext_vector_type(4))) float f32x4;

__device__ __forceinline__ unsigned short f2bf(float f){
  unsigned int u = __builtin_bit_cast(unsigned int, f);
  u += 0x7fffu + ((u >> 16) & 1u);           // round-to-nearest-even
  return (unsigned short)(u >> 16);
}
__device__ __forceinline__ float bf2f(unsigned short h){
  unsigned int u = ((unsigned int)h) << 16;
  return __builtin_bit_cast(float, u);
}
__device__ __forceinline__ float leaky(float x){ return x > 0.f ? x : 0.3f * x; }

// ---------------- BN statistics: stage 1 (per-block partial sums) ----------------
__global__ __launch_bounds__(256) void ca_stats_partial(const float* __restrict__ state,
    const int* __restrict__ agp, float* __restrict__ part, int B){
  int d = threadIdx.x;
  int ag = agp[0];
  int bPer = (B + 255) >> 8;
  int b0 = blockIdx.x * bPer;
  float sC = 0.f, ssC = 0.f, sO = 0.f, ssO = 0.f;
  for (int b = 0; b < bPer; b++){
    int bb = b0 + b;
    if (bb >= B) break;
    const float* row = state + ((size_t)bb << 12);   // *16*256
    #pragma unroll
    for (int a = 0; a < 16; a++){
      float v = row[a*256 + d];
      bool isC = (a == ag);
      sC  += isC ? v   : 0.f;
      ssC += isC ? v*v : 0.f;
      sO  += isC ? 0.f : v;
      ssO += isC ? 0.f : v*v;
    }
  }
  float* p = part + (size_t)blockIdx.x * 1024;
  p[d] = sC; p[d+256] = ssC; p[d+512] = sO; p[d+768] = ssO;
}

// ---------------- BN statistics: stage 2 (finalize rs, mean*rs), 1024 threads ----------------
__global__ __launch_bounds__(1024) void ca_stats_final(const float* __restrict__ part,
    float* __restrict__ stats, int nblk, int B){
  int d = threadIdx.x & 255, sl = threadIdx.x >> 8;
  float sC = 0.f, ssC = 0.f, sO = 0.f, ssO = 0.f;
  for (int g = sl; g < nblk; g += 4){
    const float* p = part + (size_t)g * 1024;
    sC += p[d]; ssC += p[d+256]; sO += p[d+512]; ssO += p[d+768];
  }
  __shared__ float red[4][4][256];
  red[sl][0][d] = sC; red[sl][1][d] = ssC; red[sl][2][d] = sO; red[sl][3][d] = ssO;
  __syncthreads();
  if (sl == 0){
    sC  = red[0][0][d] + red[1][0][d] + red[2][0][d] + red[3][0][d];
    ssC = red[0][1][d] + red[1][1][d] + red[2][1][d] + red[3][1][d];
    sO  = red[0][2][d] + red[1][2][d] + red[2][2][d] + red[3][2][d];
    ssO = red[0][3][d] + red[1][3][d] + red[2][3][d] + red[3][3][d];
    float nC = (float)B, nO = (float)B * 15.f;
    float mC = sC / nC, vC = ssC / nC - mC * mC;
    float mO = sO / nO, vO = ssO / nO - mO * mO;
    float rC = rsqrtf(vC + 1e-3f), rO = rsqrtf(vO + 1e-3f);
    stats[d] = rC; stats[d+256] = mC * rC; stats[d+512] = rO; stats[d+768] = mO * rO;
  }
}

// ---------------- weight prep: WsT/WcT (bf16, transposed, rs-folded) + biases ----------------
__global__ __launch_bounds__(256) void ca_prep_sc(const float* __restrict__ Ws,
    const float* __restrict__ bs, const float* __restrict__ Wc, const float* __restrict__ bc,
    const float* __restrict__ stats, unsigned short* __restrict__ WsT,
    unsigned short* __restrict__ WcT, float* __restrict__ bsp, float* __restrict__ bcp){
  int n = blockIdx.x, d = threadIdx.x;
  float rC = stats[d], mrC = stats[d+256], rO = stats[d+512], mrO = stats[d+768];
  float ws = Ws[(size_t)d*512 + n], wc = Wc[(size_t)d*512 + n];
  WsT[(size_t)n*256 + d] = f2bf(ws * rC);
  WcT[(size_t)n*256 + d] = f2bf(wc * rO);
  __shared__ float red[256];
  red[d] = mrC * ws;
  __syncthreads();
  for (int s = 128; s > 0; s >>= 1){ if (d < s) red[d] += red[d+s]; __syncthreads(); }
  if (d == 0) bsp[n] = bs[n] - red[0];
  __syncthreads();
  red[d] = mrO * wc;
  __syncthreads();
  for (int s = 128; s > 0; s >>= 1){ if (d < s) red[d] += red[d+s]; __syncthreads(); }
  if (d == 0) bcp[n] = bc[n] - red[0];
}

// ---------------- weight prep: WkT/WvT/WqT (bf16, [h*64+d][n], 1/8 folded into q) ----------------
__global__ __launch_bounds__(512) void ca_prep_kvq(const float* __restrict__ Wk,
    const float* __restrict__ Wv, const float* __restrict__ Wq,
    unsigned short* __restrict__ WkT, unsigned short* __restrict__ WvT,
    unsigned short* __restrict__ WqT){
  int c = blockIdx.x & 511, m = blockIdx.x >> 9;
  int n = threadIdx.x;
  int h = c >> 6, dd = c & 63;
  const float* W = (m == 0) ? Wk : (m == 1) ? Wv : Wq;
  unsigned short* O = (m == 0) ? WkT : (m == 1) ? WvT : WqT;
  float scale = (m == 2) ? 0.125f : 1.f;
  O[(size_t)c*512 + n] = f2bf(W[((size_t)h*512 + n)*64 + dd] * scale);
}

// ---------------- Q kernel: q = (leaky(norm(cur)@Ws + bs)) @ Wq  (32 b-rows / block) ----------------
__global__ __launch_bounds__(512) void ca_q_kernel(const float* __restrict__ state,
    const int* __restrict__ agp,
    const unsigned short* __restrict__ WsT, const float* __restrict__ bsp,
    const unsigned short* __restrict__ WqT, unsigned short* __restrict__ Qws){
  __shared__ unsigned short U[32*512];      // 32KB union: Alds (first 16KB) then SE
  __shared__ float bias_s[512];
  unsigned short* Alds = U;                 // 32 rows x 256 cols, swizzled
  unsigned short* SE = U;                   // 32 rows x 512 cols, swizzled
  int tid = threadIdx.x, lane = tid & 63, w = tid >> 6;
  int j = lane & 15, hi = lane >> 4;
  int b0 = blockIdx.x * 32;
  int ag = agp[0];

  for (int s = tid; s < 32*32; s += 512){
    int row = s >> 5, kg = s & 31;
    const float* p = state + (((size_t)(b0 + row) * 16 + ag) << 8) + kg * 8;
    f32x4 v0 = *(const f32x4*)p, v1 = *(const f32x4*)(p + 4);
    ushort8 hv;
    hv[0]=f2bf(v0[0]); hv[1]=f2bf(v0[1]); hv[2]=f2bf(v0[2]); hv[3]=f2bf(v0[3]);
    hv[4]=f2bf(v1[0]); hv[5]=f2bf(v1[1]); hv[6]=f2bf(v1[2]); hv[7]=f2bf(v1[3]);
    *(ushort8*)&Alds[row*256 + ((kg ^ (row & 7)) << 3)] = hv;
  }
  bias_s[tid & 511] = bsp[tid & 511];
  __syncthreads();

  int cb = w * 64;
  f32x4 zero4 = {0.f, 0.f, 0.f, 0.f};
  f32x4 acc[2][4];
  #pragma unroll
  for (int a1 = 0; a1 < 2; a1++)
    #pragma unroll
    for (int a2 = 0; a2 < 4; a2++) acc[a1][a2] = zero4;

  #pragma unroll
  for (int kk = 0; kk < 8; kk++){
    short8 bfr[4];
    #pragma unroll
    for (int nt = 0; nt < 4; nt++)
      bfr[nt] = *(const short8*)&WsT[(size_t)(cb + nt*16 + j)*256 + kk*32 + hi*8];
    #pragma unroll
    for (int mt = 0; mt < 2; mt++){
      int row = mt*16 + j;
      short8 afr = *(const short8*)&Alds[row*256 + ((((kk << 2) | hi) ^ (row & 7)) << 3)];
      #pragma unroll
      for (int nt = 0; nt < 4; nt++)
        acc[mt][nt] = __builtin_amdgcn_mfma_f32_16x16x32_bf16(afr, bfr[nt], acc[mt][nt], 0, 0, 0);
    }
  }
  __syncthreads();   // Alds dead; SE overlays it
  #pragma unroll
  for (int mt = 0; mt < 2; mt++)
    #pragma unroll
    for (int nt = 0; nt < 4; nt++)
      #pragma unroll
      for (int i = 0; i < 4; i++){
        int row = mt*16 + hi*4 + i, col = cb + nt*16 + j;
        float x = leaky(acc[mt][nt][i] + bias_s[col]);
        SE[row*512 + ((((col >> 3) ^ (row & 7)) << 3) | (col & 7))] = f2bf(x);
      }
  __syncthreads();

  f32x4 qa[2][4];
  #pragma unroll
  for (int a1 = 0; a1 < 2; a1++)
    #pragma unroll
    for (int a2 = 0; a2 < 4; a2++) qa[a1][a2] = zero4;
  #pragma unroll
  for (int kk = 0; kk < 16; kk++){
    short8 bfr[4];
    #pragma unroll
    for (int nt = 0; nt < 4; nt++)
      bfr[nt] = *(const short8*)&WqT[(size_t)(cb + nt*16 + j)*512 + kk*32 + hi*8];
    #pragma unroll
    for (int mt = 0; mt < 2; mt++){
      int row = mt*16 + j;
      short8 afr = *(const short8*)&SE[row*512 + ((((kk << 2) | hi) ^ (row & 7)) << 3)];
      #pragma unroll
      for (int nt = 0; nt < 4; nt++)
        qa[mt][nt] = __builtin_amdgcn_mfma_f32_16x16x32_bf16(afr, bfr[nt], qa[mt][nt], 0, 0, 0);
    }
  }
  #pragma unroll
  for (int mt = 0; mt < 2; mt++)
    #pragma unroll
    for (int nt = 0; nt < 4; nt++)
      #pragma unroll
      for (int i = 0; i < 4; i++)
        Qws[(size_t)(b0 + mt*16 + hi*4 + i)*512 + cb + nt*16 + j] = f2bf(qa[mt][nt][i]);
}

// ---------------- main fused kernel: sa_enc -> K,V -> softmax -> att ----------------
// Design B: 512 threads = 8 waves; 8 batches (128 M-rows) per block.
// Wave w = head w, computes ALL 128 rows x 64 head-cols: 8 MFMAs per B-fragment set
// (2x R3's MFMA:weight-load ratio, 4x R4's). 1 block/CU (130KB LDS), 2 waves/SIMD.
__global__ __launch_bounds__(512) void ca_main_kernel(const float* __restrict__ state,
    const int* __restrict__ agp,
    const unsigned short* __restrict__ WcT, const float* __restrict__ bcp,
    const unsigned short* __restrict__ WkT, const unsigned short* __restrict__ WvT,
    const unsigned short* __restrict__ Qws, float* __restrict__ out){
  __shared__ unsigned short U[128*512];     // 128KB union: Alds (first 64KB), then SA
  __shared__ float bias_s[512];
  unsigned short* Alds = U;                 // 128 rows x 256 cols bf16 swizzled (ai=15 pad)
  unsigned short* SA = U;                   // 128 rows x 512 cols bf16 swizzled
  int tid = threadIdx.x, lane = tid & 63, w = tid >> 6;
  int j = lane & 15, hi = lane >> 4;
  int b0 = blockIdx.x * 8;
  int ag = agp[0];

  for (int s = tid; s < 128*32; s += 512){
    int row = s >> 5, kg = s & 31;
    int bl = row >> 4, ai = row & 15;
    ushort8 hv = {0,0,0,0,0,0,0,0};
    if (ai < 15){
      int a = ai + (ai >= ag ? 1 : 0);
      const float* p = state + (((size_t)(b0 + bl) * 16 + a) << 8) + kg * 8;
      f32x4 v0 = *(const f32x4*)p, v1 = *(const f32x4*)(p + 4);
      hv[0]=f2bf(v0[0]); hv[1]=f2bf(v0[1]); hv[2]=f2bf(v0[2]); hv[3]=f2bf(v0[3]);
      hv[4]=f2bf(v1[0]); hv[5]=f2bf(v1[1]); hv[6]=f2bf(v1[2]); hv[7]=f2bf(v1[3]);
    }
    *(ushort8*)&Alds[row*256 + ((kg ^ (row & 7)) << 3)] = hv;
  }
  bias_s[tid & 511] = bcp[tid & 511];
  __syncthreads();

  int cb = w * 64;
  f32x4 zero4 = {0.f, 0.f, 0.f, 0.f};

  // ---- GEMM1: sa_enc rows [0,128) x cols [cb,cb+64)  (acc in registers)
  f32x4 acc[8][4];
  #pragma unroll
  for (int a1 = 0; a1 < 8; a1++)
    #pragma unroll
    for (int a2 = 0; a2 < 4; a2++) acc[a1][a2] = zero4;
  #pragma unroll
  for (int kk = 0; kk < 8; kk++){
    short8 bfr[4];
    #pragma unroll
    for (int nt = 0; nt < 4; nt++)
      bfr[nt] = *(const short8*)&WcT[(size_t)(cb + nt*16 + j)*256 + kk*32 + hi*8];
    #pragma unroll
    for (int mt = 0; mt < 8; mt++){
      int row = mt*16 + j;
      short8 afr = *(const short8*)&Alds[row*256 + ((((kk << 2) | hi) ^ (row & 7)) << 3)];
      #pragma unroll
      for (int nt = 0; nt < 4; nt++)
        acc[mt][nt] = __builtin_amdgcn_mfma_f32_16x16x32_bf16(afr, bfr[nt], acc[mt][nt], 0, 0, 0);
    }
  }
  __syncthreads();   // Alds dead from here; SA overlays it
  #pragma unroll
  for (int mt = 0; mt < 8; mt++)
    #pragma unroll
    for (int nt = 0; nt < 4; nt++)
      #pragma unroll
      for (int i = 0; i < 4; i++){
        int row = mt*16 + hi*4 + i, col = cb + nt*16 + j;
        float x = leaky(acc[mt][nt][i] + bias_s[col]);
        SA[row*512 + ((((col >> 3) ^ (row & 7)) << 3) | (col & 7))] = f2bf(x);
      }
  __syncthreads();

  // ---- q fragments for head w, batches b0+mt (scale folded into Wq)
  float qv[8][4];
  #pragma unroll
  for (int mt = 0; mt < 8; mt++)
    #pragma unroll
    for (int nt = 0; nt < 4; nt++)
      qv[mt][nt] = bf2f(Qws[(size_t)(b0 + mt)*512 + cb + nt*16 + j]);

  // ---- GEMM2-K: K rows [0,128), cols head w
  f32x4 ka[8][4];
  #pragma unroll
  for (int a1 = 0; a1 < 8; a1++)
    #pragma unroll
    for (int a2 = 0; a2 < 4; a2++) ka[a1][a2] = zero4;
  #pragma unroll
  for (int kk = 0; kk < 16; kk++){
    short8 bfr[4];
    #pragma unroll
    for (int nt = 0; nt < 4; nt++)
      bfr[nt] = *(const short8*)&WkT[(size_t)(cb + nt*16 + j)*512 + kk*32 + hi*8];
    #pragma unroll
    for (int mt = 0; mt < 8; mt++){
      int row = mt*16 + j;
      short8 afr = *(const short8*)&SA[row*512 + ((((kk << 2) | hi) ^ (row & 7)) << 3)];
      #pragma unroll
      for (int nt = 0; nt < 4; nt++)
        ka[mt][nt] = __builtin_amdgcn_mfma_f32_16x16x32_bf16(afr, bfr[nt], ka[mt][nt], 0, 0, 0);
    }
  }

  // ---- scores + softmax (in-register; mt == local batch index)
  float wgt[8][4];
  #pragma unroll
  for (int mt = 0; mt < 8; mt++){
    float sv[4];
    #pragma unroll
    for (int i = 0; i < 4; i++){
      float t = qv[mt][0]*ka[mt][0][i] + qv[mt][1]*ka[mt][1][i]
              + qv[mt][2]*ka[mt][2][i] + qv[mt][3]*ka[mt][3][i];
      t += __shfl_xor(t, 1); t += __shfl_xor(t, 2);
      t += __shfl_xor(t, 4); t += __shfl_xor(t, 8);
      sv[i] = t;
    }
    sv[3] = (hi == 3) ? -1e30f : sv[3];   // mask pad row a=15
    float m = fmaxf(fmaxf(sv[0], sv[1]), fmaxf(sv[2], sv[3]));
    m = fmaxf(m, __shfl_xor(m, 16)); m = fmaxf(m, __shfl_xor(m, 32));
    float e0 = __expf(sv[0]-m), e1 = __expf(sv[1]-m), e2 = __expf(sv[2]-m), e3 = __expf(sv[3]-m);
    float sum = e0 + e1 + e2 + e3;
    sum += __shfl_xor(sum, 16); sum += __shfl_xor(sum, 32);
    float inv = 1.f / sum;
    wgt[mt][0] = e0*inv; wgt[mt][1] = e1*inv; wgt[mt][2] = e2*inv; wgt[mt][3] = e3*inv;
  }

  // ---- GEMM2-V (ka registers recycled by allocator; va accumulates fresh)
  f32x4 va[8][4];
  #pragma unroll
  for (int a1 = 0; a1 < 8; a1++)
    #pragma unroll
    for (int a2 = 0; a2 < 4; a2++) va[a1][a2] = zero4;
  #pragma unroll
  for (int kk = 0; kk < 16; kk++){
    short8 bfr[4];
    #pragma unroll
    for (int nt = 0; nt < 4; nt++)
      bfr[nt] = *(const short8*)&WvT[(size_t)(cb + nt*16 + j)*512 + kk*32 + hi*8];
    #pragma unroll
    for (int mt = 0; mt < 8; mt++){
      int row = mt*16 + j;
      short8 afr = *(const short8*)&SA[row*512 + ((((kk << 2) | hi) ^ (row & 7)) << 3)];
      #pragma unroll
      for (int nt = 0; nt < 4; nt++)
        va[mt][nt] = __builtin_amdgcn_mfma_f32_16x16x32_bf16(afr, bfr[nt], va[mt][nt], 0, 0, 0);
    }
  }

  // ---- att = sum_a w * leaky(V); butterfly over hi groups; coalesced store
  #pragma unroll
  for (int mt = 0; mt < 8; mt++){
    float ap0 = 0.f, ap1 = 0.f, ap2 = 0.f, ap3 = 0.f;
    #pragma unroll
    for (int i = 0; i < 4; i++){
      float wv = wgt[mt][i];
      ap0 += wv * leaky(va[mt][0][i]);
      ap1 += wv * leaky(va[mt][1][i]);
      ap2 += wv * leaky(va[mt][2][i]);
      ap3 += wv * leaky(va[mt][3][i]);
    }
    ap0 += __shfl_xor(ap0, 16); ap0 += __shfl_xor(ap0, 32);
    ap1 += __shfl_xor(ap1, 16); ap1 += __shfl_xor(ap1, 32);
    ap2 += __shfl_xor(ap2, 16); ap2 += __shfl_xor(ap2, 32);
    ap3 += __shfl_xor(ap3, 16); ap3 += __shfl_xor(ap3, 32);
    float val = (hi == 0) ? ap0 : (hi == 1) ? ap1 : (hi == 2) ? ap2 : ap3;
    out[(size_t)(b0 + mt)*512 + cb + lane] = val;
  }
}

extern "C" void kernel_launch(void* const* d_in, const int* in_sizes, int n_in,
                              void* d_out, int out_size, void* d_ws, size_t ws_size,
                              hipStream_t stream) {
  const float* state = (const float*)d_in[0];
  const int*   agp   = (const int*)d_in[1];
  const float* Ws    = (const float*)d_in[2];
  const float* bs    = (const float*)d_in[3];
  const float* Wc    = (const float*)d_in[4];
  const float* bc    = (const float*)d_in[5];
  const float* Wk    = (const float*)d_in[6];
  const float* Wq    = (const float*)d_in[7];
  const float* Wv    = (const float*)d_in[8];
  float* out = (float*)d_out;
  int B = in_sizes[0] / 4096;   // state is (B,16,256)

  char* wsb = (char*)d_ws;
  float* part  = (float*)wsb;                                   // 256*1024*4 = 1 MB
  float* stats = (float*)(wsb + (1 << 20));                     // 4 KB
  float* bsp   = (float*)(wsb + (1 << 20) + 4096);              // 2 KB
  float* bcp   = (float*)(wsb + (1 << 20) + 6144);              // 2 KB
  unsigned short* WsT = (unsigned short*)(wsb + (1 << 20) + 8192);
  unsigned short* WcT = WsT + 512*256;
  unsigned short* WkT = WcT + 512*256;
  unsigned short* WvT = WkT + 512*512;
  unsigned short* WqT = WvT + 512*512;
  unsigned short* Qws = WqT + 512*512;   // B*512 bf16 = 8 MB; total ws ~11.1 MB

  hipLaunchKernelGGL(ca_stats_partial, dim3(256), dim3(256), 0, stream, state, agp, part, B);
  hipLaunchKernelGGL(ca_stats_final,   dim3(1),   dim3(1024), 0, stream, part, stats, 256, B);
  hipLaunchKernelGGL(ca_prep_sc,       dim3(512), dim3(256), 0, stream, Ws, bs, Wc, bc, stats, WsT, WcT, bsp, bcp);
  hipLaunchKernelGGL(ca_prep_kvq,      dim3(1536),dim3(512), 0, stream, Wk, Wv, Wq, WkT, WvT, WqT);
  hipLaunchKernelGGL(ca_q_kernel,      dim3(B/32),dim3(512), 0, stream, state, agp, WsT, bsp, WqT, Qws);
  hipLaunchKernelGGL(ca_main_kernel,   dim3(B/8), dim3(512), 0, stream, state, agp, WcT, bcp, WkT, WvT, Qws, out);
}

// Round 6
// 442.554 us; speedup vs baseline: 1.6935x; 1.6935x over previous
//
#include <hip/hip_runtime.h>

typedef __attribute__((ext_vector_type(8))) short short8;
typedef __attribute__((ext_vector_type(8))) unsigned short ushort8;
typedef __attribute__((ext_vector_type(4))) float f32x4;

__device__ __forceinline__ unsigned short f2bf(float f){
  unsigned int u = __builtin_bit_cast(unsigned int, f);
  u += 0x7fffu + ((u >> 16) & 1u);           // round-to-nearest-even
  return (unsigned short)(u >> 16);
}
__device__ __forceinline__ float bf2f(unsigned short h){
  unsigned int u = ((unsigned int)h) << 16;
  return __builtin_bit_cast(float, u);
}
__device__ __forceinline__ float leaky(float x){ return x > 0.f ? x : 0.3f * x; }

// ---------------- BN statistics: stage 1 (per-block partial sums) ----------------
__global__ __launch_bounds__(256) void ca_stats_partial(const float* __restrict__ state,
    const int* __restrict__ agp, float* __restrict__ part, int B){
  int d = threadIdx.x;
  int ag = agp[0];
  int bPer = (B + 255) >> 8;
  int b0 = blockIdx.x * bPer;
  float sC = 0.f, ssC = 0.f, sO = 0.f, ssO = 0.f;
  for (int b = 0; b < bPer; b++){
    int bb = b0 + b;
    if (bb >= B) break;
    const float* row = state + ((size_t)bb << 12);   // *16*256
    #pragma unroll
    for (int a = 0; a < 16; a++){
      float v = row[a*256 + d];
      bool isC = (a == ag);
      sC  += isC ? v   : 0.f;
      ssC += isC ? v*v : 0.f;
      sO  += isC ? 0.f : v;
      ssO += isC ? 0.f : v*v;
    }
  }
  float* p = part + (size_t)blockIdx.x * 1024;
  p[d] = sC; p[d+256] = ssC; p[d+512] = sO; p[d+768] = ssO;
}

// ---------------- BN statistics: stage 2 (finalize rs, mean*rs), 1024 threads ----------------
__global__ __launch_bounds__(1024) void ca_stats_final(const float* __restrict__ part,
    float* __restrict__ stats, int nblk, int B){
  int d = threadIdx.x & 255, sl = threadIdx.x >> 8;
  float sC = 0.f, ssC = 0.f, sO = 0.f, ssO = 0.f;
  for (int g = sl; g < nblk; g += 4){
    const float* p = part + (size_t)g * 1024;
    sC += p[d]; ssC += p[d+256]; sO += p[d+512]; ssO += p[d+768];
  }
  __shared__ float red[4][4][256];
  red[sl][0][d] = sC; red[sl][1][d] = ssC; red[sl][2][d] = sO; red[sl][3][d] = ssO;
  __syncthreads();
  if (sl == 0){
    sC  = red[0][0][d] + red[1][0][d] + red[2][0][d] + red[3][0][d];
    ssC = red[0][1][d] + red[1][1][d] + red[2][1][d] + red[3][1][d];
    sO  = red[0][2][d] + red[1][2][d] + red[2][2][d] + red[3][2][d];
    ssO = red[0][3][d] + red[1][3][d] + red[2][3][d] + red[3][3][d];
    float nC = (float)B, nO = (float)B * 15.f;
    float mC = sC / nC, vC = ssC / nC - mC * mC;
    float mO = sO / nO, vO = ssO / nO - mO * mO;
    float rC = rsqrtf(vC + 1e-3f), rO = rsqrtf(vO + 1e-3f);
    stats[d] = rC; stats[d+256] = mC * rC; stats[d+512] = rO; stats[d+768] = mO * rO;
  }
}

// ---------------- weight prep: WsT/WcT (bf16, transposed, rs-folded) + biases ----------------
__global__ __launch_bounds__(256) void ca_prep_sc(const float* __restrict__ Ws,
    const float* __restrict__ bs, const float* __restrict__ Wc, const float* __restrict__ bc,
    const float* __restrict__ stats, unsigned short* __restrict__ WsT,
    unsigned short* __restrict__ WcT, float* __restrict__ bsp, float* __restrict__ bcp){
  int n = blockIdx.x, d = threadIdx.x;
  float rC = stats[d], mrC = stats[d+256], rO = stats[d+512], mrO = stats[d+768];
  float ws = Ws[(size_t)d*512 + n], wc = Wc[(size_t)d*512 + n];
  WsT[(size_t)n*256 + d] = f2bf(ws * rC);
  WcT[(size_t)n*256 + d] = f2bf(wc * rO);
  __shared__ float red[256];
  red[d] = mrC * ws;
  __syncthreads();
  for (int s = 128; s > 0; s >>= 1){ if (d < s) red[d] += red[d+s]; __syncthreads(); }
  if (d == 0) bsp[n] = bs[n] - red[0];
  __syncthreads();
  red[d] = mrO * wc;
  __syncthreads();
  for (int s = 128; s > 0; s >>= 1){ if (d < s) red[d] += red[d+s]; __syncthreads(); }
  if (d == 0) bcp[n] = bc[n] - red[0];
}

// ---------------- weight prep: WkT/WvT/WqT (bf16, [h*64+d][n], 1/8 folded into q) ----------------
__global__ __launch_bounds__(512) void ca_prep_kvq(const float* __restrict__ Wk,
    const float* __restrict__ Wv, const float* __restrict__ Wq,
    unsigned short* __restrict__ WkT, unsigned short* __restrict__ WvT,
    unsigned short* __restrict__ WqT){
  int c = blockIdx.x & 511, m = blockIdx.x >> 9;
  int n = threadIdx.x;
  int h = c >> 6, dd = c & 63;
  const float* W = (m == 0) ? Wk : (m == 1) ? Wv : Wq;
  unsigned short* O = (m == 0) ? WkT : (m == 1) ? WvT : WqT;
  float scale = (m == 2) ? 0.125f : 1.f;
  O[(size_t)c*512 + n] = f2bf(W[((size_t)h*512 + n)*64 + dd] * scale);
}

// ---------------- Q kernel: q = (leaky(norm(cur)@Ws + bs)) @ Wq  (32 b-rows / block) ----------------
__global__ __launch_bounds__(512) void ca_q_kernel(const float* __restrict__ state,
    const int* __restrict__ agp,
    const unsigned short* __restrict__ WsT, const float* __restrict__ bsp,
    const unsigned short* __restrict__ WqT, unsigned short* __restrict__ Qws){
  __shared__ unsigned short U[32*512];      // 32KB union: Alds (first 16KB) then SE
  __shared__ float bias_s[512];
  unsigned short* Alds = U;                 // 32 rows x 256 cols, swizzled
  unsigned short* SE = U;                   // 32 rows x 512 cols, swizzled
  int tid = threadIdx.x, lane = tid & 63, w = tid >> 6;
  int j = lane & 15, hi = lane >> 4;
  int b0 = blockIdx.x * 32;
  int ag = agp[0];

  for (int s = tid; s < 32*32; s += 512){
    int row = s >> 5, kg = s & 31;
    const float* p = state + (((size_t)(b0 + row) * 16 + ag) << 8) + kg * 8;
    f32x4 v0 = *(const f32x4*)p, v1 = *(const f32x4*)(p + 4);
    ushort8 hv;
    hv[0]=f2bf(v0[0]); hv[1]=f2bf(v0[1]); hv[2]=f2bf(v0[2]); hv[3]=f2bf(v0[3]);
    hv[4]=f2bf(v1[0]); hv[5]=f2bf(v1[1]); hv[6]=f2bf(v1[2]); hv[7]=f2bf(v1[3]);
    *(ushort8*)&Alds[row*256 + ((kg ^ (row & 7)) << 3)] = hv;
  }
  bias_s[tid & 511] = bsp[tid & 511];
  __syncthreads();

  int cb = w * 64;
  f32x4 zero4 = {0.f, 0.f, 0.f, 0.f};
  f32x4 acc[2][4];
  #pragma unroll
  for (int a1 = 0; a1 < 2; a1++)
    #pragma unroll
    for (int a2 = 0; a2 < 4; a2++) acc[a1][a2] = zero4;

  #pragma unroll
  for (int kk = 0; kk < 8; kk++){
    short8 bfr[4];
    #pragma unroll
    for (int nt = 0; nt < 4; nt++)
      bfr[nt] = *(const short8*)&WsT[(size_t)(cb + nt*16 + j)*256 + kk*32 + hi*8];
    #pragma unroll
    for (int mt = 0; mt < 2; mt++){
      int row = mt*16 + j;
      short8 afr = *(const short8*)&Alds[row*256 + ((((kk << 2) | hi) ^ (row & 7)) << 3)];
      #pragma unroll
      for (int nt = 0; nt < 4; nt++)
        acc[mt][nt] = __builtin_amdgcn_mfma_f32_16x16x32_bf16(afr, bfr[nt], acc[mt][nt], 0, 0, 0);
    }
  }
  __syncthreads();   // Alds dead; SE overlays it
  #pragma unroll
  for (int mt = 0; mt < 2; mt++)
    #pragma unroll
    for (int nt = 0; nt < 4; nt++)
      #pragma unroll
      for (int i = 0; i < 4; i++){
        int row = mt*16 + hi*4 + i, col = cb + nt*16 + j;
        float x = leaky(acc[mt][nt][i] + bias_s[col]);
        SE[row*512 + ((((col >> 3) ^ (row & 7)) << 3) | (col & 7))] = f2bf(x);
      }
  __syncthreads();

  f32x4 qa[2][4];
  #pragma unroll
  for (int a1 = 0; a1 < 2; a1++)
    #pragma unroll
    for (int a2 = 0; a2 < 4; a2++) qa[a1][a2] = zero4;
  #pragma unroll
  for (int kk = 0; kk < 16; kk++){
    short8 bfr[4];
    #pragma unroll
    for (int nt = 0; nt < 4; nt++)
      bfr[nt] = *(const short8*)&WqT[(size_t)(cb + nt*16 + j)*512 + kk*32 + hi*8];
    #pragma unroll
    for (int mt = 0; mt < 2; mt++){
      int row = mt*16 + j;
      short8 afr = *(const short8*)&SE[row*512 + ((((kk << 2) | hi) ^ (row & 7)) << 3)];
      #pragma unroll
      for (int nt = 0; nt < 4; nt++)
        qa[mt][nt] = __builtin_amdgcn_mfma_f32_16x16x32_bf16(afr, bfr[nt], qa[mt][nt], 0, 0, 0);
    }
  }
  #pragma unroll
  for (int mt = 0; mt < 2; mt++)
    #pragma unroll
    for (int nt = 0; nt < 4; nt++)
      #pragma unroll
      for (int i = 0; i < 4; i++)
        Qws[(size_t)(b0 + mt*16 + hi*4 + i)*512 + cb + nt*16 + j] = f2bf(qa[mt][nt][i]);
}

// ---------------- main fused kernel: sa_enc -> K,V -> softmax -> att (4 b / block) ----------------
// 512 threads = 8 waves, wave w = head w, 64 M-rows. __launch_bounds__(512,2):
// 2 blocks/CU -> 16 waves/CU -> 4 waves/SIMD -> 128-unified-reg budget.
// (Empirical: 2nd arg behaves as blocks/CU on this toolchain; R2: arg=4 -> 64 VGPR.)
__global__ __launch_bounds__(512, 2) void ca_main_kernel(const float* __restrict__ state,
    const int* __restrict__ agp,
    const unsigned short* __restrict__ WcT, const float* __restrict__ bcp,
    const unsigned short* __restrict__ WkT, const unsigned short* __restrict__ WvT,
    const unsigned short* __restrict__ Qws, float* __restrict__ out){
  __shared__ unsigned short U[64*512];      // 64KB union: Alds (first 32KB), then SA
  __shared__ float bias_s[512];
  unsigned short* Alds = U;                 // 64 rows x 256 cols bf16 swizzled (ai=15 pad)
  unsigned short* SA = U;                   // 64 rows x 512 cols bf16 swizzled
  int tid = threadIdx.x, lane = tid & 63, w = tid >> 6;
  int j = lane & 15, hi = lane >> 4;
  int b0 = blockIdx.x * 4;
  int ag = agp[0];

  for (int s = tid; s < 2048; s += 512){
    int row = s >> 5, kg = s & 31;
    int bl = row >> 4, ai = row & 15;
    ushort8 hv = {0,0,0,0,0,0,0,0};
    if (ai < 15){
      int a = ai + (ai >= ag ? 1 : 0);
      const float* p = state + (((size_t)(b0 + bl) * 16 + a) << 8) + kg * 8;
      f32x4 v0 = *(const f32x4*)p, v1 = *(const f32x4*)(p + 4);
      hv[0]=f2bf(v0[0]); hv[1]=f2bf(v0[1]); hv[2]=f2bf(v0[2]); hv[3]=f2bf(v0[3]);
      hv[4]=f2bf(v1[0]); hv[5]=f2bf(v1[1]); hv[6]=f2bf(v1[2]); hv[7]=f2bf(v1[3]);
    }
    *(ushort8*)&Alds[row*256 + ((kg ^ (row & 7)) << 3)] = hv;
  }
  bias_s[tid & 511] = bcp[tid & 511];
  __syncthreads();

  int cb = w * 64;
  f32x4 zero4 = {0.f, 0.f, 0.f, 0.f};

  // ---- GEMM1: sa_enc[:, cb:cb+64] (acc in registers)
  f32x4 acc[4][4];
  #pragma unroll
  for (int a1 = 0; a1 < 4; a1++)
    #pragma unroll
    for (int a2 = 0; a2 < 4; a2++) acc[a1][a2] = zero4;
  #pragma unroll
  for (int kk = 0; kk < 8; kk++){
    short8 bfr[4];
    #pragma unroll
    for (int nt = 0; nt < 4; nt++)
      bfr[nt] = *(const short8*)&WcT[(size_t)(cb + nt*16 + j)*256 + kk*32 + hi*8];
    #pragma unroll
    for (int mt = 0; mt < 4; mt++){
      int row = mt*16 + j;
      short8 afr = *(const short8*)&Alds[row*256 + ((((kk << 2) | hi) ^ (row & 7)) << 3)];
      #pragma unroll
      for (int nt = 0; nt < 4; nt++)
        acc[mt][nt] = __builtin_amdgcn_mfma_f32_16x16x32_bf16(afr, bfr[nt], acc[mt][nt], 0, 0, 0);
    }
  }
  __syncthreads();   // Alds dead from here; SA overlays it
  #pragma unroll
  for (int mt = 0; mt < 4; mt++)
    #pragma unroll
    for (int nt = 0; nt < 4; nt++)
      #pragma unroll
      for (int i = 0; i < 4; i++){
        int row = mt*16 + hi*4 + i, col = cb + nt*16 + j;
        float x = leaky(acc[mt][nt][i] + bias_s[col]);
        SA[row*512 + ((((col >> 3) ^ (row & 7)) << 3) | (col & 7))] = f2bf(x);
      }
  __syncthreads();

  // ---- GEMM2-K: K_head_w = sa_enc @ WkT[cb..cb+64]
  f32x4 ka[4][4];
  #pragma unroll
  for (int a1 = 0; a1 < 4; a1++)
    #pragma unroll
    for (int a2 = 0; a2 < 4; a2++) ka[a1][a2] = zero4;
  #pragma unroll
  for (int kk = 0; kk < 16; kk++){
    short8 bfr[4];
    #pragma unroll
    for (int nt = 0; nt < 4; nt++)
      bfr[nt] = *(const short8*)&WkT[(size_t)(cb + nt*16 + j)*512 + kk*32 + hi*8];
    #pragma unroll
    for (int mt = 0; mt < 4; mt++){
      int row = mt*16 + j;
      short8 afr = *(const short8*)&SA[row*512 + ((((kk << 2) | hi) ^ (row & 7)) << 3)];
      #pragma unroll
      for (int nt = 0; nt < 4; nt++)
        ka[mt][nt] = __builtin_amdgcn_mfma_f32_16x16x32_bf16(afr, bfr[nt], ka[mt][nt], 0, 0, 0);
    }
  }

  // ---- q fragments loaded here (only needed for softmax; keeps GEMM2-K pressure low)
  float qv[4][4];
  #pragma unroll
  for (int mt = 0; mt < 4; mt++)
    #pragma unroll
    for (int nt = 0; nt < 4; nt++)
      qv[mt][nt] = bf2f(Qws[(size_t)(b0 + mt)*512 + cb + nt*16 + j]);

  // ---- scores + softmax (fully in-register; mt == local batch index)
  float wgt[4][4];
  #pragma unroll
  for (int mt = 0; mt < 4; mt++){
    float sv[4];
    #pragma unroll
    for (int i = 0; i < 4; i++){
      float t = qv[mt][0]*ka[mt][0][i] + qv[mt][1]*ka[mt][1][i]
              + qv[mt][2]*ka[mt][2][i] + qv[mt][3]*ka[mt][3][i];
      t += __shfl_xor(t, 1); t += __shfl_xor(t, 2);
      t += __shfl_xor(t, 4); t += __shfl_xor(t, 8);
      sv[i] = t;
    }
    sv[3] = (hi == 3) ? -1e30f : sv[3];   // mask pad row a=15
    float m = fmaxf(fmaxf(sv[0], sv[1]), fmaxf(sv[2], sv[3]));
    m = fmaxf(m, __shfl_xor(m, 16)); m = fmaxf(m, __shfl_xor(m, 32));
    float e0 = __expf(sv[0]-m), e1 = __expf(sv[1]-m), e2 = __expf(sv[2]-m), e3 = __expf(sv[3]-m);
    float sum = e0 + e1 + e2 + e3;
    sum += __shfl_xor(sum, 16); sum += __shfl_xor(sum, 32);
    float inv = 1.f / sum;
    wgt[mt][0] = e0*inv; wgt[mt][1] = e1*inv; wgt[mt][2] = e2*inv; wgt[mt][3] = e3*inv;
  }

  // ---- GEMM2-V
  f32x4 va[4][4];
  #pragma unroll
  for (int a1 = 0; a1 < 4; a1++)
    #pragma unroll
    for (int a2 = 0; a2 < 4; a2++) va[a1][a2] = zero4;
  #pragma unroll
  for (int kk = 0; kk < 16; kk++){
    short8 bfr[4];
    #pragma unroll
    for (int nt = 0; nt < 4; nt++)
      bfr[nt] = *(const short8*)&WvT[(size_t)(cb + nt*16 + j)*512 + kk*32 + hi*8];
    #pragma unroll
    for (int mt = 0; mt < 4; mt++){
      int row = mt*16 + j;
      short8 afr = *(const short8*)&SA[row*512 + ((((kk << 2) | hi) ^ (row & 7)) << 3)];
      #pragma unroll
      for (int nt = 0; nt < 4; nt++)
        va[mt][nt] = __builtin_amdgcn_mfma_f32_16x16x32_bf16(afr, bfr[nt], va[mt][nt], 0, 0, 0);
    }
  }

  // ---- att = sum_a w * leaky(V); butterfly over hi groups; coalesced store
  #pragma unroll
  for (int mt = 0; mt < 4; mt++){
    float ap0 = 0.f, ap1 = 0.f, ap2 = 0.f, ap3 = 0.f;
    #pragma unroll
    for (int i = 0; i < 4; i++){
      float wv = wgt[mt][i];
      ap0 += wv * leaky(va[mt][0][i]);
      ap1 += wv * leaky(va[mt][1][i]);
      ap2 += wv * leaky(va[mt][2][i]);
      ap3 += wv * leaky(va[mt][3][i]);
    }
    ap0 += __shfl_xor(ap0, 16); ap0 += __shfl_xor(ap0, 32);
    ap1 += __shfl_xor(ap1, 16); ap1 += __shfl_xor(ap1, 32);
    ap2 += __shfl_xor(ap2, 16); ap2 += __shfl_xor(ap2, 32);
    ap3 += __shfl_xor(ap3, 16); ap3 += __shfl_xor(ap3, 32);
    float val = (hi == 0) ? ap0 : (hi == 1) ? ap1 : (hi == 2) ? ap2 : ap3;
    out[(size_t)(b0 + mt)*512 + cb + lane] = val;
  }
}

extern "C" void kernel_launch(void* const* d_in, const int* in_sizes, int n_in,
                              void* d_out, int out_size, void* d_ws, size_t ws_size,
                              hipStream_t stream) {
  const float* state = (const float*)d_in[0];
  const int*   agp   = (const int*)d_in[1];
  const float* Ws    = (const float*)d_in[2];
  const float* bs    = (const float*)d_in[3];
  const float* Wc    = (const float*)d_in[4];
  const float* bc    = (const float*)d_in[5];
  const float* Wk    = (const float*)d_in[6];
  const float* Wq    = (const float*)d_in[7];
  const float* Wv    = (const float*)d_in[8];
  float* out = (float*)d_out;
  int B = in_sizes[0] / 4096;   // state is (B,16,256)

  char* wsb = (char*)d_ws;
  float* part  = (float*)wsb;                                   // 256*1024*4 = 1 MB
  float* stats = (float*)(wsb + (1 << 20));                     // 4 KB
  float* bsp   = (float*)(wsb + (1 << 20) + 4096);              // 2 KB
  float* bcp   = (float*)(wsb + (1 << 20) + 6144);              // 2 KB
  unsigned short* WsT = (unsigned short*)(wsb + (1 << 20) + 8192);
  unsigned short* WcT = WsT + 512*256;
  unsigned short* WkT = WcT + 512*256;
  unsigned short* WvT = WkT + 512*512;
  unsigned short* WqT = WvT + 512*512;
  unsigned short* Qws = WqT + 512*512;   // B*512 bf16 = 8 MB; total ws ~11.1 MB

  hipLaunchKernelGGL(ca_stats_partial, dim3(256), dim3(256), 0, stream, state, agp, part, B);
  hipLaunchKernelGGL(ca_stats_final,   dim3(1),   dim3(1024), 0, stream, part, stats, 256, B);
  hipLaunchKernelGGL(ca_prep_sc,       dim3(512), dim3(256), 0, stream, Ws, bs, Wc, bc, stats, WsT, WcT, bsp, bcp);
  hipLaunchKernelGGL(ca_prep_kvq,      dim3(1536),dim3(512), 0, stream, Wk, Wv, Wq, WkT, WvT, WqT);
  hipLaunchKernelGGL(ca_q_kernel,      dim3(B/32),dim3(512), 0, stream, state, agp, WsT, bsp, WqT, Qws);
  hipLaunchKernelGGL(ca_main_kernel,   dim3(B/4), dim3(512), 0, stream, state, agp, WcT, bcp, WkT, WvT, Qws, out);
}